// Round 19
// baseline (1314.429 us; speedup 1.0000x reference)
//
#include <hip/hip_runtime.h>
#include <hip/hip_bf16.h>

#define HWSZ (192*192)

typedef __attribute__((ext_vector_type(8))) short short8v;
typedef __attribute__((ext_vector_type(4))) float f32x4;

// prep'd weight element counts
#define WG_N  331776   // conv w: [tap][oc][c]  9*192*192
#define WQ2_N 110592   // qkv  w: [576][192] straight cast
#define PW2_N 36864    // proj w: [192][192] straight cast
#define W1_N  73728    // glu  w: [384][192] straight cast
#define WBYTES ((size_t)2*(WG_N+WQ2_N+PW2_N+W1_N))

// ---------------------------------------------------------------------------
// prep: cast/reorder weights to bf16
// ---------------------------------------------------------------------------
__global__ __launch_bounds__(256)
void prep_weights(const float* __restrict__ w2_w, const float* __restrict__ qkv_w,
                  const float* __restrict__ proj_w, const float* __restrict__ w1_w,
                  __hip_bfloat16* __restrict__ wg, __hip_bfloat16* __restrict__ wq,
                  __hip_bfloat16* __restrict__ pw, __hip_bfloat16* __restrict__ w1b)
{
    int i = blockIdx.x*256 + threadIdx.x;
    if (i < WG_N) {
        int tap = i / 36864; int r = i - tap*36864;
        int oc = r / 192;    int c = r - oc*192;
        wg[i] = __float2bfloat16(w2_w[((size_t)oc*192 + c)*9 + tap]);
    } else if (i < WG_N + WQ2_N) {
        int j = i - WG_N;  wq[j] = __float2bfloat16(qkv_w[j]);
    } else if (i < WG_N + WQ2_N + PW2_N) {
        int j = i - WG_N - WQ2_N;  pw[j] = __float2bfloat16(proj_w[j]);
    } else if (i < WG_N + WQ2_N + PW2_N + W1_N) {
        int j = i - WG_N - WQ2_N - PW2_N;  w1b[j] = __float2bfloat16(w1_w[j]);
    }
}

// ---------------------------------------------------------------------------
// Fused window kernel (exact R18 text — 466us proven).
// Fragment convention (HW-verified R2-R18):
//   A/B-frag: lane(kg,lx): element [non-K = lx][k = kg*8 + j], j contiguous
//   D:        lane(kg,lx): [row = kg*4 + r][col = lx]
// LDS: Xs 25.6K + Os 25.6K + scr 18.4K + bias 8.4K = 76.5KB -> 2 blocks/CU.
// ---------------------------------------------------------------------------
__global__ __launch_bounds__(256, 2)
void wac_fused(const float* __restrict__ x,
               const __hip_bfloat16* __restrict__ wq, const float* __restrict__ qkv_b,
               const __hip_bfloat16* __restrict__ pw, const float* __restrict__ proj_b,
               const __hip_bfloat16* __restrict__ w1b, const float* __restrict__ w1_b,
               const float* __restrict__ bias_tab,
               __hip_bfloat16* __restrict__ g_ws, float* __restrict__ out)
{
    __shared__ __align__(16) __hip_bfloat16 Xs[64][200];   // bf16 x; later g stage
    __shared__ __align__(16) __hip_bfloat16 Os[64][200];   // O heads; later out stage
    __shared__ __align__(16) __hip_bfloat16 scr[4][2304];  // per-wave D->frag scratch
    __shared__ __align__(16) __hip_bfloat16 bias_bf[64][66];

    const int tid = threadIdx.x;
    // XCD swizzle: blocks n%8==k handle image k's windows -> x locality per XCD
    const int wid = (blockIdx.x & 7)*576 + (blockIdx.x >> 3);
    const int img = wid / 576;
    const int wr  = wid - img*576;
    const int wi  = wr / 24;
    const int wj  = wr - wi*24;

    const float* xb = x + (size_t)img*192*HWSZ + (size_t)(wi*8)*192 + wj*8;
    for (int i = tid; i < 12288; i += 256) {
        int c = i >> 6, t = i & 63;
        Xs[t][c] = __float2bfloat16(xb[(size_t)c*HWSZ + (t>>3)*192 + (t&7)]);
    }
    for (int i = tid; i < 4096; i += 256) {
        int tq = i >> 6, tk = i & 63;
        bias_bf[tq][tk] = __float2bfloat16(
            bias_tab[((tq>>3)-(tk>>3)+7)*15 + ((tq&7)-(tk&7)+7)]);
    }
    __syncthreads();                                      // B1

    const int lane = tid & 63;
    const int wv   = tid >> 6;        // wave = head
    const int lx   = lane & 15;
    const int kg   = lane >> 4;
    __hip_bfloat16* S = scr[wv];
    const short8v z8 = {0,0,0,0,0,0,0,0};
    const float scale = 0.14433756729740643f; // 1/sqrt(48)

    // ---------------- QKV for head wv: merged single pass over kc ----------
    short8v qAf[4][2], kBf[4][2], vBf[3][2];
    {
        f32x4 qa[9][4];
        #pragma unroll
        for (int j9=0;j9<9;j9++)
            #pragma unroll
            for (int n=0;n<4;n++) qa[j9][n] = (f32x4){0.f,0.f,0.f,0.f};

        #pragma unroll
        for (int kc=0; kc<6; ++kc) {
            short8v bfX[4];
            #pragma unroll
            for (int n=0;n<4;n++)
                bfX[n] = *(const short8v*)&Xs[n*16+lx][kc*32+kg*8];
            __builtin_amdgcn_s_setprio(1);
            #pragma unroll
            for (int j9=0; j9<9; ++j9) {
                const int reg = j9/3, mm = j9 - reg*3;
                short8v af = *(const short8v*)
                    &wq[(size_t)(reg*192 + wv*48 + mm*16 + lx)*192 + kc*32 + kg*8];
                #pragma unroll
                for (int n=0;n<4;n++)
                    qa[j9][n] = __builtin_amdgcn_mfma_f32_16x16x32_bf16(
                                    af, bfX[n], qa[j9][n], 0,0,0);
            }
            __builtin_amdgcn_s_setprio(0);
        }

        // ---- repack q (reg 0) and k (reg 1): two half-passes over t ----
        #pragma unroll
        for (int reg=0; reg<2; ++reg) {
            const int jrow0 = reg*192 + wv*48;
            float b4[3][4];
            #pragma unroll
            for (int mm=0;mm<3;mm++)
                #pragma unroll
                for (int r=0;r<4;r++) b4[mm][r] = qkv_b[jrow0 + mm*16 + kg*4 + r];
            #pragma unroll
            for (int hp=0; hp<2; ++hp) {
                #pragma unroll
                for (int mm=0;mm<3;mm++)
                    #pragma unroll
                    for (int nl=0;nl<2;nl++) {
                        union { ushort4 u; __hip_bfloat16 e[4]; } pk;
                        #pragma unroll
                        for (int r=0;r<4;r++)
                            pk.e[r] = __float2bfloat16(qa[reg*3+mm][hp*2+nl][r] + b4[mm][r]);
                        *(ushort4*)&S[(nl*16+lx)*56 + mm*16 + kg*4] = pk.u;
                    }
                #pragma unroll
                for (int mtl=0; mtl<2; ++mtl) {
                    short8v f0 = *(const short8v*)&S[(mtl*16+lx)*56 + kg*8];
                    short8v f1 = (kg<2) ? *(const short8v*)&S[(mtl*16+lx)*56 + 32 + kg*8] : z8;
                    if (reg==0) { qAf[hp*2+mtl][0]=f0; qAf[hp*2+mtl][1]=f1; }
                    else        { kBf[hp*2+mtl][0]=f0; kBf[hp*2+mtl][1]=f1; }
                }
            }
        }
        // ---- repack v (reg 2): three passes over d-tiles ----
        {
            const int jrow0 = 2*192 + wv*48;
            float b4[3][4];
            #pragma unroll
            for (int mm=0;mm<3;mm++)
                #pragma unroll
                for (int r=0;r<4;r++) b4[mm][r] = qkv_b[jrow0 + mm*16 + kg*4 + r];
            #pragma unroll
            for (int mm=0;mm<3;mm++) {
                #pragma unroll
                for (int n=0;n<4;n++)
                    #pragma unroll
                    for (int r=0;r<4;r++)
                        S[(kg*4+r)*72 + n*16+lx] =
                            __float2bfloat16(qa[6+mm][n][r] + b4[mm][r]);
                vBf[mm][0] = *(const short8v*)&S[lx*72 + kg*8];
                vBf[mm][1] = *(const short8v*)&S[lx*72 + 32 + kg*8];
            }
        }
    }

    // ---------------- scores (K=48: kc1 half-zero) ----------------
    f32x4 sa[4][4];
    #pragma unroll
    for (int m=0;m<4;m++)
        #pragma unroll
        for (int n=0;n<4;n++) sa[m][n] = (f32x4){0.f,0.f,0.f,0.f};
    __builtin_amdgcn_s_setprio(1);
    #pragma unroll
    for (int kc2=0; kc2<2; ++kc2)
        #pragma unroll
        for (int m=0;m<4;m++)
            #pragma unroll
            for (int n=0;n<4;n++)
                sa[m][n] = __builtin_amdgcn_mfma_f32_16x16x32_bf16(
                               qAf[m][kc2], kBf[n][kc2], sa[m][n], 0,0,0);
    __builtin_amdgcn_s_setprio(0);

    // ---------------- softmax + PV per 32-row half ----------------
    #pragma unroll
    for (int hp=0; hp<2; ++hp) {
        #pragma unroll
        for (int ml=0; ml<2; ++ml) {
            const int m = hp*2 + ml;
            #pragma unroll
            for (int r=0;r<4;r++) {
                const int trow = m*16 + kg*4 + r;
                float s[4];
                float mx = -1e30f;
                #pragma unroll
                for (int n=0;n<4;n++){
                    s[n] = sa[m][n][r]*scale + __bfloat162float(bias_bf[trow][n*16+lx]);
                    mx = fmaxf(mx, s[n]);
                }
                mx = fmaxf(mx, __shfl_xor(mx,1));
                mx = fmaxf(mx, __shfl_xor(mx,2));
                mx = fmaxf(mx, __shfl_xor(mx,4));
                mx = fmaxf(mx, __shfl_xor(mx,8));
                float l = 0.f;
                #pragma unroll
                for (int n=0;n<4;n++){ s[n] = __expf(s[n]-mx); l += s[n]; }
                l += __shfl_xor(l,1); l += __shfl_xor(l,2);
                l += __shfl_xor(l,4); l += __shfl_xor(l,8);
                const float inv = 1.f/l;
                #pragma unroll
                for (int n=0;n<4;n++)
                    S[(ml*16+kg*4+r)*72 + n*16+lx] = __float2bfloat16(s[n]*inv);
            }
        }
        short8v pA[2][2];
        #pragma unroll
        for (int ml=0; ml<2; ++ml) {
            pA[ml][0] = *(const short8v*)&S[(ml*16+lx)*72 + kg*8];
            pA[ml][1] = *(const short8v*)&S[(ml*16+lx)*72 + 32 + kg*8];
        }
        f32x4 oa[2][3];
        #pragma unroll
        for (int ml=0;ml<2;ml++)
            #pragma unroll
            for (int n=0;n<3;n++) oa[ml][n] = (f32x4){0.f,0.f,0.f,0.f};
        __builtin_amdgcn_s_setprio(1);
        #pragma unroll
        for (int kc2=0; kc2<2; ++kc2)
            #pragma unroll
            for (int ml=0;ml<2;ml++)
                #pragma unroll
                for (int n=0;n<3;n++)
                    oa[ml][n] = __builtin_amdgcn_mfma_f32_16x16x32_bf16(
                                    pA[ml][kc2], vBf[n][kc2], oa[ml][n], 0,0,0);
        __builtin_amdgcn_s_setprio(0);
        #pragma unroll
        for (int ml=0;ml<2;ml++)
            #pragma unroll
            for (int n=0;n<3;n++)
                #pragma unroll
                for (int r=0;r<4;r++)
                    Os[(hp*2+ml)*16+kg*4+r][wv*48 + n*16+lx] =
                        __float2bfloat16(oa[ml][n][r]);
    }
    __syncthreads();                                      // B2: O complete

    // ---------------- proj (wave = 48 oc rows) + residual ----------------
    f32x4 pa[3][4];
    #pragma unroll
    for (int m=0;m<3;m++)
        #pragma unroll
        for (int n=0;n<4;n++) pa[m][n] = (f32x4){0.f,0.f,0.f,0.f};
    #pragma unroll
    for (int kc=0; kc<6; ++kc) {
        short8v bo[4];
        #pragma unroll
        for (int n=0;n<4;n++)
            bo[n] = *(const short8v*)&Os[n*16+lx][kc*32+kg*8];
        __builtin_amdgcn_s_setprio(1);
        #pragma unroll
        for (int mm=0; mm<3; ++mm) {
            short8v ap = *(const short8v*)
                &pw[(size_t)(wv*48 + mm*16 + lx)*192 + kc*32 + kg*8];
            #pragma unroll
            for (int n=0;n<4;n++)
                pa[mm][n] = __builtin_amdgcn_mfma_f32_16x16x32_bf16(
                                ap, bo[n], pa[mm][n], 0,0,0);
        }
        __builtin_amdgcn_s_setprio(0);
    }
    // out = bf16(x) + proj + pb; write global; keep values for staging
    const size_t obase = (size_t)img*192*HWSZ + (size_t)(wi*8)*192 + wj*8;
    #pragma unroll
    for (int mm=0; mm<3; ++mm) {
        const int oc0 = wv*48 + mm*16 + kg*4;
        float pb4[4];
        #pragma unroll
        for (int r=0;r<4;r++) pb4[r] = proj_b[oc0+r];
        #pragma unroll
        for (int n=0;n<4;n++) {
            const int t = n*16 + lx;
            const size_t po = (size_t)(t>>3)*192 + (t&7);
            #pragma unroll
            for (int r=0;r<4;r++) {
                float v = pa[mm][n][r] + pb4[r] + __bfloat162float(Xs[t][oc0+r]);
                pa[mm][n][r] = v;
                out[obase + (size_t)(oc0+r)*HWSZ + po] = v;
            }
        }
    }
    __syncthreads();                                      // B3: O reads done
    #pragma unroll
    for (int mm=0; mm<3; ++mm) {
        const int oc0 = wv*48 + mm*16 + kg*4;
        #pragma unroll
        for (int n=0;n<4;n++) {
            const int t = n*16 + lx;
            union { ushort4 u; __hip_bfloat16 e[4]; } pk;
            #pragma unroll
            for (int r=0;r<4;r++) pk.e[r] = __float2bfloat16(pa[mm][n][r]);
            *(ushort4*)&Os[t][oc0] = pk.u;
        }
    }
    __syncthreads();                                      // B4: out stage ready

    // ---------------- GLU (wave = 96 rows: paired a/b tiles) ----------------
    f32x4 ga[6][4];
    #pragma unroll
    for (int m=0;m<6;m++)
        #pragma unroll
        for (int n=0;n<4;n++) ga[m][n] = (f32x4){0.f,0.f,0.f,0.f};
    #pragma unroll
    for (int kc=0; kc<6; ++kc) {
        short8v bf2[4];
        #pragma unroll
        for (int n=0;n<4;n++)
            bf2[n] = *(const short8v*)&Os[n*16+lx][kc*32+kg*8];
        __builtin_amdgcn_s_setprio(1);
        #pragma unroll
        for (int mm=0; mm<6; ++mm) {
            const int mrow = ((mm<3) ? (3*wv+mm) : (12 + 3*wv + mm-3))*16 + lx;
            short8v af = *(const short8v*)&w1b[(size_t)mrow*192 + kc*32 + kg*8];
            #pragma unroll
            for (int n=0;n<4;n++)
                ga[mm][n] = __builtin_amdgcn_mfma_f32_16x16x32_bf16(
                                af, bf2[n], ga[mm][n], 0,0,0);
        }
        __builtin_amdgcn_s_setprio(0);
    }
    // GLU combine -> stage g into Xs (dead after residual)
    #pragma unroll
    for (int mm=0; mm<3; ++mm) {
        const int oc0 = (3*wv+mm)*16 + kg*4;
        float ba4[4], bb4[4];
        #pragma unroll
        for (int r=0;r<4;r++){ ba4[r] = w1_b[oc0+r]; bb4[r] = w1_b[oc0+r+192]; }
        #pragma unroll
        for (int n=0;n<4;n++) {
            union { ushort4 u; __hip_bfloat16 e[4]; } pk;
            #pragma unroll
            for (int r=0;r<4;r++) {
                const float a  = ga[mm][n][r]   + ba4[r];
                const float bv = ga[mm+3][n][r] + bb4[r];
                pk.e[r] = __float2bfloat16(a * (1.f/(1.f+__expf(-bv))));
            }
            *(ushort4*)&Xs[n*16+lx][oc0] = pk.u;
        }
    }
    __syncthreads();                                      // B5: g stage ready

    // coalesced g write (pixel-major [img][y][x][c])
    for (int i = tid; i < 1536; i += 256) {
        const int t = i / 24, c0 = (i - t*24)*8;
        const size_t ga_ = ((size_t)img*HWSZ +
                            (size_t)(wi*8 + (t>>3))*192 + wj*8 + (t&7))*192 + c0;
        *(uint4*)&g_ws[ga_] = *(const uint4*)&Xs[t][c0];
    }
}

// ---------------------------------------------------------------------------
// K3: 3x3 conv via 9-tap shifted MFMA GEMM.
// R19: ky-SPLIT weight staging — wt holds one ky-row of taps (3x96x32 =
// 18.4KB); LDS = gt 20.7K + wt 18.4K = 39.2KB -> 3 blocks/CU at VGPR<=85
// (launch_bounds(512,6)).  6 barriers per K-chunk, drains overlapped
// across 3 independent blocks.
// ---------------------------------------------------------------------------
#define KC 32
__global__ __launch_bounds__(512, 6)
void conv_mfma(const __hip_bfloat16* __restrict__ g,
               const __hip_bfloat16* __restrict__ wg,
               const float* __restrict__ w2_b, float* __restrict__ out, int img0)
{
    __shared__ __align__(16) __hip_bfloat16 gt[18*18*32];   // [iy][ix][c]
    __shared__ __align__(16) __hip_bfloat16 wt[3*96*32];    // [kx][ocl][c] (one ky row)

    // XCD-contiguous swizzle: 2304 = 8 * 288, bijective
    int bid = (blockIdx.x & 7)*288 + (blockIdx.x >> 3);
    const int tX = bid % 12; bid /= 12;
    const int tY = bid % 12; bid /= 12;
    const int ob = bid & 1;  bid >>= 1;
    const int bimg_l = bid;
    const int tx0 = tX*16, ty0 = tY*16, oc0 = ob*96;

    const int tid  = threadIdx.x;
    const int lane = tid & 63;
    const int wv   = tid >> 6;      // 0..7
    const int wm   = wv >> 2;       // oc half (48)
    const int wq   = wv & 3;        // pixel quarter (4 rows)
    const int lx   = lane & 15;
    const int kg   = lane >> 4;

    f32x4 acc[3][4];
    #pragma unroll
    for (int m=0;m<3;m++)
        #pragma unroll
        for (int n=0;n<4;n++) acc[m][n] = (f32x4){0.f,0.f,0.f,0.f};

    const size_t gbase = (size_t)bimg_l*HWSZ;

    #pragma unroll 1
    for (int c0 = 0; c0 < 192; c0 += KC) {
        __syncthreads();   // all reads of gt/wt from previous chunk done
        // g tile (18x18 halo, replication clamp), 32 channels
        for (int idx = tid; idx < 1296; idx += 512) {
            int px = idx >> 2, part = idx & 3;
            int iy = px / 18, ix = px - iy*18;
            int gy = min(max(ty0 + iy - 1, 0), 191);
            int gx = min(max(tx0 + ix - 1, 0), 191);
            *(uint4*)&gt[(iy*18+ix)*32 + part*8] =
                *(const uint4*)&g[(gbase + (size_t)gy*192 + gx)*192 + c0 + part*8];
        }
        #pragma unroll 1
        for (int ky=0; ky<3; ++ky) {
            // stage this ky-row's 3 taps: 3 x 96 oc x 32 c
            for (int idx = tid; idx < 1152; idx += 512) {
                int kx_ = idx / 384; int rr = idx - kx_*384;
                int ocl = rr >> 2, part = rr & 3;
                *(uint4*)&wt[(kx_*96+ocl)*32 + part*8] =
                    *(const uint4*)&wg[(size_t)(ky*3+kx_)*36864 +
                                       (size_t)(oc0+ocl)*192 + c0 + part*8];
            }
            __syncthreads();    // staging visible (also covers gt on ky=0)

            __builtin_amdgcn_s_setprio(1);
            #pragma unroll
            for (int kx=0; kx<3; ++kx) {
                short8v a[3];
                #pragma unroll
                for (int m=0;m<3;m++)
                    a[m] = *(const short8v*)&wt[(kx*96 + wm*48 + m*16 + lx)*32 + kg*8];
                #pragma unroll
                for (int n=0;n<4;n++) {
                    short8v bb = *(const short8v*)
                        &gt[((wq*4 + n + ky)*18 + lx + kx)*32 + kg*8];
                    #pragma unroll
                    for (int m=0;m<3;m++)
                        acc[m][n] = __builtin_amdgcn_mfma_f32_16x16x32_bf16(
                                        a[m], bb, acc[m][n], 0, 0, 0);
                }
            }
            __builtin_amdgcn_s_setprio(0);
            if (ky < 2) __syncthreads();   // wt reads done before re-staging
        }
    }

    #pragma unroll
    for (int m=0;m<3;m++) {
        const int ocb_ = oc0 + wm*48 + m*16 + kg*4;
        #pragma unroll
        for (int n=0;n<4;n++) {
            const int y = ty0 + wq*4 + n;
            const int xx = tx0 + lx;
            #pragma unroll
            for (int r=0;r<4;r++) {
                const int oc = ocb_ + r;
                const size_t o = ((size_t)((img0+bimg_l)*192+oc))*HWSZ + (size_t)y*192 + xx;
                float v = acc[m][n][r] + w2_b[oc];
                v = (v >= 0.f) ? v : 0.2f*v;
                out[o] += v;
            }
        }
    }
}

// ---------------------------------------------------------------------------
extern "C" void kernel_launch(void* const* d_in, const int* in_sizes, int n_in,
                              void* d_out, int out_size, void* d_ws, size_t ws_size,
                              hipStream_t stream)
{
    const float* x        = (const float*)d_in[0];
    const float* qkv_w    = (const float*)d_in[1];
    const float* qkv_b    = (const float*)d_in[2];
    const float* proj_w   = (const float*)d_in[3];
    const float* proj_b   = (const float*)d_in[4];
    const float* bias_tab = (const float*)d_in[5];
    const float* w1_w     = (const float*)d_in[6];
    const float* w1_b     = (const float*)d_in[7];
    const float* w2_w     = (const float*)d_in[8];
    const float* w2_b     = (const float*)d_in[9];
    float* out = (float*)d_out;

    char* base = (char*)d_ws;
    __hip_bfloat16* wg  = (__hip_bfloat16*)base;
    __hip_bfloat16* wqp = (__hip_bfloat16*)(base + (size_t)WG_N*2);
    __hip_bfloat16* pwp = (__hip_bfloat16*)(base + (size_t)(WG_N+WQ2_N)*2);
    __hip_bfloat16* w1b = (__hip_bfloat16*)(base + (size_t)(WG_N+WQ2_N+PW2_N)*2);
    __hip_bfloat16* g_ws = (__hip_bfloat16*)(base + WBYTES);   // 113.2 MB

    prep_weights<<<2160, 256, 0, stream>>>(w2_w, qkv_w, proj_w, w1_w, wg, wqp, pwp, w1b);
    wac_fused   <<<4608, 256, 0, stream>>>(x, wqp, qkv_b, pwp, proj_b, w1b, w1_b,
                                           bias_tab, g_ws, out);
    conv_mfma   <<<2304, 512, 0, stream>>>(g_ws, wg, w2_b, out, 0);
}

// Round 20
// 670.668 us; speedup vs baseline: 1.9599x; 1.9599x over previous
//
#include <hip/hip_runtime.h>
#include <hip/hip_bf16.h>

#define HWSZ (192*192)

typedef __attribute__((ext_vector_type(8))) short short8v;
typedef __attribute__((ext_vector_type(4))) float f32x4;

// prep'd weight element counts
#define WG_N  331776   // conv w: [tap][oc][c]  9*192*192
#define WQ2_N 110592   // qkv  w: [576][192] straight cast
#define PW2_N 36864    // proj w: [192][192] straight cast
#define W1_N  73728    // glu  w: [384][192] straight cast
#define WBYTES ((size_t)2*(WG_N+WQ2_N+PW2_N+W1_N))

// ---------------------------------------------------------------------------
// prep: cast/reorder weights to bf16
// ---------------------------------------------------------------------------
__global__ __launch_bounds__(256)
void prep_weights(const float* __restrict__ w2_w, const float* __restrict__ qkv_w,
                  const float* __restrict__ proj_w, const float* __restrict__ w1_w,
                  __hip_bfloat16* __restrict__ wg, __hip_bfloat16* __restrict__ wq,
                  __hip_bfloat16* __restrict__ pw, __hip_bfloat16* __restrict__ w1b)
{
    int i = blockIdx.x*256 + threadIdx.x;
    if (i < WG_N) {
        int tap = i / 36864; int r = i - tap*36864;
        int oc = r / 192;    int c = r - oc*192;
        wg[i] = __float2bfloat16(w2_w[((size_t)oc*192 + c)*9 + tap]);
    } else if (i < WG_N + WQ2_N) {
        int j = i - WG_N;  wq[j] = __float2bfloat16(qkv_w[j]);
    } else if (i < WG_N + WQ2_N + PW2_N) {
        int j = i - WG_N - WQ2_N;  pw[j] = __float2bfloat16(proj_w[j]);
    } else if (i < WG_N + WQ2_N + PW2_N + W1_N) {
        int j = i - WG_N - WQ2_N - PW2_N;  w1b[j] = __float2bfloat16(w1_w[j]);
    }
}

// ---------------------------------------------------------------------------
// Fused window kernel (exact R13/R16 text — 466us proven).
// Fragment convention (HW-verified R2-R19):
//   A/B-frag: lane(kg,lx): element [non-K = lx][k = kg*8 + j], j contiguous
//   D:        lane(kg,lx): [row = kg*4 + r][col = lx]
// LDS: Xs 25.6K + Os 25.6K + scr 18.4K + bias 8.4K = 76.5KB -> 2 blocks/CU.
// ---------------------------------------------------------------------------
__global__ __launch_bounds__(256, 2)
void wac_fused(const float* __restrict__ x,
               const __hip_bfloat16* __restrict__ wq, const float* __restrict__ qkv_b,
               const __hip_bfloat16* __restrict__ pw, const float* __restrict__ proj_b,
               const __hip_bfloat16* __restrict__ w1b, const float* __restrict__ w1_b,
               const float* __restrict__ bias_tab,
               __hip_bfloat16* __restrict__ g_ws, float* __restrict__ out)
{
    __shared__ __align__(16) __hip_bfloat16 Xs[64][200];   // bf16 x; later g stage
    __shared__ __align__(16) __hip_bfloat16 Os[64][200];   // O heads; later out stage
    __shared__ __align__(16) __hip_bfloat16 scr[4][2304];  // per-wave D->frag scratch
    __shared__ __align__(16) __hip_bfloat16 bias_bf[64][66];

    const int tid = threadIdx.x;
    // XCD swizzle: blocks n%8==k handle image k's windows -> x locality per XCD
    const int wid = (blockIdx.x & 7)*576 + (blockIdx.x >> 3);
    const int img = wid / 576;
    const int wr  = wid - img*576;
    const int wi  = wr / 24;
    const int wj  = wr - wi*24;

    const float* xb = x + (size_t)img*192*HWSZ + (size_t)(wi*8)*192 + wj*8;
    for (int i = tid; i < 12288; i += 256) {
        int c = i >> 6, t = i & 63;
        Xs[t][c] = __float2bfloat16(xb[(size_t)c*HWSZ + (t>>3)*192 + (t&7)]);
    }
    for (int i = tid; i < 4096; i += 256) {
        int tq = i >> 6, tk = i & 63;
        bias_bf[tq][tk] = __float2bfloat16(
            bias_tab[((tq>>3)-(tk>>3)+7)*15 + ((tq&7)-(tk&7)+7)]);
    }
    __syncthreads();                                      // B1

    const int lane = tid & 63;
    const int wv   = tid >> 6;        // wave = head
    const int lx   = lane & 15;
    const int kg   = lane >> 4;
    __hip_bfloat16* S = scr[wv];
    const short8v z8 = {0,0,0,0,0,0,0,0};
    const float scale = 0.14433756729740643f; // 1/sqrt(48)

    // ---------------- QKV for head wv: merged single pass over kc ----------
    short8v qAf[4][2], kBf[4][2], vBf[3][2];
    {
        f32x4 qa[9][4];
        #pragma unroll
        for (int j9=0;j9<9;j9++)
            #pragma unroll
            for (int n=0;n<4;n++) qa[j9][n] = (f32x4){0.f,0.f,0.f,0.f};

        #pragma unroll
        for (int kc=0; kc<6; ++kc) {
            short8v bfX[4];
            #pragma unroll
            for (int n=0;n<4;n++)
                bfX[n] = *(const short8v*)&Xs[n*16+lx][kc*32+kg*8];
            #pragma unroll
            for (int j9=0; j9<9; ++j9) {
                const int reg = j9/3, mm = j9 - reg*3;
                short8v af = *(const short8v*)
                    &wq[(size_t)(reg*192 + wv*48 + mm*16 + lx)*192 + kc*32 + kg*8];
                #pragma unroll
                for (int n=0;n<4;n++)
                    qa[j9][n] = __builtin_amdgcn_mfma_f32_16x16x32_bf16(
                                    af, bfX[n], qa[j9][n], 0,0,0);
            }
        }

        // ---- repack q (reg 0) and k (reg 1): two half-passes over t ----
        // (packed ushort4 writes — R8-proven form)
        #pragma unroll
        for (int reg=0; reg<2; ++reg) {
            const int jrow0 = reg*192 + wv*48;
            float b4[3][4];
            #pragma unroll
            for (int mm=0;mm<3;mm++)
                #pragma unroll
                for (int r=0;r<4;r++) b4[mm][r] = qkv_b[jrow0 + mm*16 + kg*4 + r];
            #pragma unroll
            for (int hp=0; hp<2; ++hp) {
                #pragma unroll
                for (int mm=0;mm<3;mm++)
                    #pragma unroll
                    for (int nl=0;nl<2;nl++) {
                        union { ushort4 u; __hip_bfloat16 e[4]; } pk;
                        #pragma unroll
                        for (int r=0;r<4;r++)
                            pk.e[r] = __float2bfloat16(qa[reg*3+mm][hp*2+nl][r] + b4[mm][r]);
                        *(ushort4*)&S[(nl*16+lx)*56 + mm*16 + kg*4] = pk.u;
                    }
                #pragma unroll
                for (int mtl=0; mtl<2; ++mtl) {
                    short8v f0 = *(const short8v*)&S[(mtl*16+lx)*56 + kg*8];
                    short8v f1 = (kg<2) ? *(const short8v*)&S[(mtl*16+lx)*56 + 32 + kg*8] : z8;
                    if (reg==0) { qAf[hp*2+mtl][0]=f0; qAf[hp*2+mtl][1]=f1; }
                    else        { kBf[hp*2+mtl][0]=f0; kBf[hp*2+mtl][1]=f1; }
                }
            }
        }
        // ---- repack v (reg 2): three passes over d-tiles ----
        {
            const int jrow0 = 2*192 + wv*48;
            float b4[3][4];
            #pragma unroll
            for (int mm=0;mm<3;mm++)
                #pragma unroll
                for (int r=0;r<4;r++) b4[mm][r] = qkv_b[jrow0 + mm*16 + kg*4 + r];
            #pragma unroll
            for (int mm=0;mm<3;mm++) {
                #pragma unroll
                for (int n=0;n<4;n++)
                    #pragma unroll
                    for (int r=0;r<4;r++)
                        S[(kg*4+r)*72 + n*16+lx] =
                            __float2bfloat16(qa[6+mm][n][r] + b4[mm][r]);
                vBf[mm][0] = *(const short8v*)&S[lx*72 + kg*8];
                vBf[mm][1] = *(const short8v*)&S[lx*72 + 32 + kg*8];
            }
        }
    }

    // ---------------- scores (K=48: kc1 half-zero) ----------------
    f32x4 sa[4][4];
    #pragma unroll
    for (int m=0;m<4;m++)
        #pragma unroll
        for (int n=0;n<4;n++) sa[m][n] = (f32x4){0.f,0.f,0.f,0.f};
    #pragma unroll
    for (int kc2=0; kc2<2; ++kc2)
        #pragma unroll
        for (int m=0;m<4;m++)
            #pragma unroll
            for (int n=0;n<4;n++)
                sa[m][n] = __builtin_amdgcn_mfma_f32_16x16x32_bf16(
                               qAf[m][kc2], kBf[n][kc2], sa[m][n], 0,0,0);

    // ---------------- softmax + PV per 32-row half ----------------
    #pragma unroll
    for (int hp=0; hp<2; ++hp) {
        #pragma unroll
        for (int ml=0; ml<2; ++ml) {
            const int m = hp*2 + ml;
            #pragma unroll
            for (int r=0;r<4;r++) {
                const int trow = m*16 + kg*4 + r;
                float s[4];
                float mx = -1e30f;
                #pragma unroll
                for (int n=0;n<4;n++){
                    s[n] = sa[m][n][r]*scale + __bfloat162float(bias_bf[trow][n*16+lx]);
                    mx = fmaxf(mx, s[n]);
                }
                mx = fmaxf(mx, __shfl_xor(mx,1));
                mx = fmaxf(mx, __shfl_xor(mx,2));
                mx = fmaxf(mx, __shfl_xor(mx,4));
                mx = fmaxf(mx, __shfl_xor(mx,8));
                float l = 0.f;
                #pragma unroll
                for (int n=0;n<4;n++){ s[n] = __expf(s[n]-mx); l += s[n]; }
                l += __shfl_xor(l,1); l += __shfl_xor(l,2);
                l += __shfl_xor(l,4); l += __shfl_xor(l,8);
                const float inv = 1.f/l;
                #pragma unroll
                for (int n=0;n<4;n++)
                    S[(ml*16+kg*4+r)*72 + n*16+lx] = __float2bfloat16(s[n]*inv);
            }
        }
        short8v pA[2][2];
        #pragma unroll
        for (int ml=0; ml<2; ++ml) {
            pA[ml][0] = *(const short8v*)&S[(ml*16+lx)*72 + kg*8];
            pA[ml][1] = *(const short8v*)&S[(ml*16+lx)*72 + 32 + kg*8];
        }
        f32x4 oa[2][3];
        #pragma unroll
        for (int ml=0;ml<2;ml++)
            #pragma unroll
            for (int n=0;n<3;n++) oa[ml][n] = (f32x4){0.f,0.f,0.f,0.f};
        #pragma unroll
        for (int kc2=0; kc2<2; ++kc2)
            #pragma unroll
            for (int ml=0;ml<2;ml++)
                #pragma unroll
                for (int n=0;n<3;n++)
                    oa[ml][n] = __builtin_amdgcn_mfma_f32_16x16x32_bf16(
                                    pA[ml][kc2], vBf[n][kc2], oa[ml][n], 0,0,0);
        #pragma unroll
        for (int ml=0;ml<2;ml++)
            #pragma unroll
            for (int n=0;n<3;n++)
                #pragma unroll
                for (int r=0;r<4;r++)
                    Os[(hp*2+ml)*16+kg*4+r][wv*48 + n*16+lx] =
                        __float2bfloat16(oa[ml][n][r]);
    }
    __syncthreads();                                      // B2: O complete

    // ---------------- proj (wave = 48 oc rows) + residual ----------------
    f32x4 pa[3][4];
    #pragma unroll
    for (int m=0;m<3;m++)
        #pragma unroll
        for (int n=0;n<4;n++) pa[m][n] = (f32x4){0.f,0.f,0.f,0.f};
    #pragma unroll
    for (int kc=0; kc<6; ++kc) {
        short8v bo[4];
        #pragma unroll
        for (int n=0;n<4;n++)
            bo[n] = *(const short8v*)&Os[n*16+lx][kc*32+kg*8];
        #pragma unroll
        for (int mm=0; mm<3; ++mm) {
            short8v ap = *(const short8v*)
                &pw[(size_t)(wv*48 + mm*16 + lx)*192 + kc*32 + kg*8];
            #pragma unroll
            for (int n=0;n<4;n++)
                pa[mm][n] = __builtin_amdgcn_mfma_f32_16x16x32_bf16(
                                ap, bo[n], pa[mm][n], 0,0,0);
        }
    }
    // out = bf16(x) + proj + pb; write global; keep values for staging
    const size_t obase = (size_t)img*192*HWSZ + (size_t)(wi*8)*192 + wj*8;
    #pragma unroll
    for (int mm=0; mm<3; ++mm) {
        const int oc0 = wv*48 + mm*16 + kg*4;
        float pb4[4];
        #pragma unroll
        for (int r=0;r<4;r++) pb4[r] = proj_b[oc0+r];
        #pragma unroll
        for (int n=0;n<4;n++) {
            const int t = n*16 + lx;
            const size_t po = (size_t)(t>>3)*192 + (t&7);
            #pragma unroll
            for (int r=0;r<4;r++) {
                float v = pa[mm][n][r] + pb4[r] + __bfloat162float(Xs[t][oc0+r]);
                pa[mm][n][r] = v;
                out[obase + (size_t)(oc0+r)*HWSZ + po] = v;
            }
        }
    }
    __syncthreads();                                      // B3: O reads done
    #pragma unroll
    for (int mm=0; mm<3; ++mm) {
        const int oc0 = wv*48 + mm*16 + kg*4;
        #pragma unroll
        for (int n=0;n<4;n++) {
            const int t = n*16 + lx;
            union { ushort4 u; __hip_bfloat16 e[4]; } pk;
            #pragma unroll
            for (int r=0;r<4;r++) pk.e[r] = __float2bfloat16(pa[mm][n][r]);
            *(ushort4*)&Os[t][oc0] = pk.u;
        }
    }
    __syncthreads();                                      // B4: out stage ready

    // ---------------- GLU (wave = 96 rows: paired a/b tiles) ----------------
    f32x4 ga[6][4];
    #pragma unroll
    for (int m=0;m<6;m++)
        #pragma unroll
        for (int n=0;n<4;n++) ga[m][n] = (f32x4){0.f,0.f,0.f,0.f};
    #pragma unroll
    for (int kc=0; kc<6; ++kc) {
        short8v bf2[4];
        #pragma unroll
        for (int n=0;n<4;n++)
            bf2[n] = *(const short8v*)&Os[n*16+lx][kc*32+kg*8];
        #pragma unroll
        for (int mm=0; mm<6; ++mm) {
            const int mrow = ((mm<3) ? (3*wv+mm) : (12 + 3*wv + mm-3))*16 + lx;
            short8v af = *(const short8v*)&w1b[(size_t)mrow*192 + kc*32 + kg*8];
            #pragma unroll
            for (int n=0;n<4;n++)
                ga[mm][n] = __builtin_amdgcn_mfma_f32_16x16x32_bf16(
                                af, bf2[n], ga[mm][n], 0,0,0);
        }
    }
    // GLU combine -> stage g into Xs (dead after residual)
    #pragma unroll
    for (int mm=0; mm<3; ++mm) {
        const int oc0 = (3*wv+mm)*16 + kg*4;
        float ba4[4], bb4[4];
        #pragma unroll
        for (int r=0;r<4;r++){ ba4[r] = w1_b[oc0+r]; bb4[r] = w1_b[oc0+r+192]; }
        #pragma unroll
        for (int n=0;n<4;n++) {
            union { ushort4 u; __hip_bfloat16 e[4]; } pk;
            #pragma unroll
            for (int r=0;r<4;r++) {
                const float a  = ga[mm][n][r]   + ba4[r];
                const float bv = ga[mm+3][n][r] + bb4[r];
                pk.e[r] = __float2bfloat16(a * (1.f/(1.f+__expf(-bv))));
            }
            *(ushort4*)&Xs[n*16+lx][oc0] = pk.u;
        }
    }
    __syncthreads();                                      // B5: g stage ready

    // coalesced g write (pixel-major [img][y][x][c])
    for (int i = tid; i < 1536; i += 256) {
        const int t = i / 24, c0 = (i - t*24)*8;
        const size_t ga_ = ((size_t)img*HWSZ +
                            (size_t)(wi*8 + (t>>3))*192 + wj*8 + (t&7))*192 + c0;
        *(uint4*)&g_ws[ga_] = *(const uint4*)&Xs[t][c0];
    }
}

// ---------------------------------------------------------------------------
// K3: 3x3 conv via 9-tap shifted MFMA GEMM (exact R16 text — ~190us proven:
// 16x16 px x 96 oc, 512 thr, LDS-staged weights, kx-outer + 6-row B cache).
// LDS = gt 20.7K + wt 55.3K = 76KB -> 2 blocks/CU (4 waves/SIMD).
// ---------------------------------------------------------------------------
#define KC 32
__global__ __launch_bounds__(512, 4)
void conv_mfma(const __hip_bfloat16* __restrict__ g,
               const __hip_bfloat16* __restrict__ wg,
               const float* __restrict__ w2_b, float* __restrict__ out, int img0)
{
    __shared__ __align__(16) __hip_bfloat16 gt[18*18*32];   // [iy][ix][c]
    __shared__ __align__(16) __hip_bfloat16 wt[9*96*32];    // [tap][ocl][c]

    // XCD-contiguous swizzle: 2304 = 8 * 288, bijective
    int bid = (blockIdx.x & 7)*288 + (blockIdx.x >> 3);
    const int tX = bid % 12; bid /= 12;
    const int tY = bid % 12; bid /= 12;
    const int ob = bid & 1;  bid >>= 1;
    const int bimg_l = bid;
    const int tx0 = tX*16, ty0 = tY*16, oc0 = ob*96;

    const int tid  = threadIdx.x;
    const int lane = tid & 63;
    const int wv   = tid >> 6;      // 0..7
    const int wm   = wv >> 2;       // oc half (48)
    const int wq   = wv & 3;        // pixel quarter (4 rows)
    const int lx   = lane & 15;
    const int kg   = lane >> 4;

    f32x4 acc[3][4];
    #pragma unroll
    for (int m=0;m<3;m++)
        #pragma unroll
        for (int n=0;n<4;n++) acc[m][n] = (f32x4){0.f,0.f,0.f,0.f};

    const size_t gbase = (size_t)bimg_l*HWSZ;

    for (int c0 = 0; c0 < 192; c0 += KC) {
        for (int idx = tid; idx < 1296; idx += 512) {
            int px = idx >> 2, part = idx & 3;
            int iy = px / 18, ix = px - iy*18;
            int gy = min(max(ty0 + iy - 1, 0), 191);
            int gx = min(max(tx0 + ix - 1, 0), 191);
            *(uint4*)&gt[(iy*18+ix)*32 + part*8] =
                *(const uint4*)&g[(gbase + (size_t)gy*192 + gx)*192 + c0 + part*8];
        }
        for (int idx = tid; idx < 3456; idx += 512) {
            int tap = idx / 384; int rr = idx - tap*384;
            int ocl = rr >> 2, part = rr & 3;
            *(uint4*)&wt[(tap*96+ocl)*32 + part*8] =
                *(const uint4*)&wg[(size_t)tap*36864 + (size_t)(oc0+ocl)*192 + c0 + part*8];
        }
        __syncthreads();

        // kx-outer: load 6 B-row-frags once, reuse across ky (bb6[n+ky])
        #pragma unroll
        for (int kx=0; kx<3; ++kx) {
            short8v bb6[6];
            #pragma unroll
            for (int j=0;j<6;j++)
                bb6[j] = *(const short8v*)&gt[((wq*4 + j)*18 + lx + kx)*32 + kg*8];
            #pragma unroll
            for (int ky=0; ky<3; ++ky) {
                const int tap = ky*3+kx;
                short8v a[3];
                #pragma unroll
                for (int m=0;m<3;m++)
                    a[m] = *(const short8v*)&wt[(tap*96 + wm*48 + m*16 + lx)*32 + kg*8];
                #pragma unroll
                for (int m=0;m<3;m++)
                    #pragma unroll
                    for (int n=0;n<4;n++)
                        acc[m][n] = __builtin_amdgcn_mfma_f32_16x16x32_bf16(
                                        a[m], bb6[n+ky], acc[m][n], 0, 0, 0);
            }
        }
        __syncthreads();
    }

    #pragma unroll
    for (int m=0;m<3;m++) {
        const int ocb_ = oc0 + wm*48 + m*16 + kg*4;
        #pragma unroll
        for (int n=0;n<4;n++) {
            const int y = ty0 + wq*4 + n;
            const int xx = tx0 + lx;
            #pragma unroll
            for (int r=0;r<4;r++) {
                const int oc = ocb_ + r;
                const size_t o = ((size_t)((img0+bimg_l)*192+oc))*HWSZ + (size_t)y*192 + xx;
                float v = acc[m][n][r] + w2_b[oc];
                v = (v >= 0.f) ? v : 0.2f*v;
                out[o] += v;
            }
        }
    }
}

// ---------------------------------------------------------------------------
extern "C" void kernel_launch(void* const* d_in, const int* in_sizes, int n_in,
                              void* d_out, int out_size, void* d_ws, size_t ws_size,
                              hipStream_t stream)
{
    const float* x        = (const float*)d_in[0];
    const float* qkv_w    = (const float*)d_in[1];
    const float* qkv_b    = (const float*)d_in[2];
    const float* proj_w   = (const float*)d_in[3];
    const float* proj_b   = (const float*)d_in[4];
    const float* bias_tab = (const float*)d_in[5];
    const float* w1_w     = (const float*)d_in[6];
    const float* w1_b     = (const float*)d_in[7];
    const float* w2_w     = (const float*)d_in[8];
    const float* w2_b     = (const float*)d_in[9];
    float* out = (float*)d_out;

    char* base = (char*)d_ws;
    __hip_bfloat16* wg  = (__hip_bfloat16*)base;
    __hip_bfloat16* wqp = (__hip_bfloat16*)(base + (size_t)WG_N*2);
    __hip_bfloat16* pwp = (__hip_bfloat16*)(base + (size_t)(WG_N+WQ2_N)*2);
    __hip_bfloat16* w1b = (__hip_bfloat16*)(base + (size_t)(WG_N+WQ2_N+PW2_N)*2);
    __hip_bfloat16* g_ws = (__hip_bfloat16*)(base + WBYTES);   // 113.2 MB

    prep_weights<<<2160, 256, 0, stream>>>(w2_w, qkv_w, proj_w, w1_w, wg, wqp, pwp, w1b);
    wac_fused   <<<4608, 256, 0, stream>>>(x, wqp, qkv_b, pwp, proj_b, w1b, w1_b,
                                           bias_tab, g_ws, out);
    conv_mfma   <<<2304, 512, 0, stream>>>(g_ws, wg, w2_b, out, 0);
}